// Round 1
// baseline (629.874 us; speedup 1.0000x reference)
//
#include <hip/hip_runtime.h>

typedef float    f32x4  __attribute__((ext_vector_type(4)));
typedef float    f32x16 __attribute__((ext_vector_type(16)));
typedef _Float16 f16x4  __attribute__((ext_vector_type(4)));
typedef _Float16 f16x8  __attribute__((ext_vector_type(8)));

#define N_IMG 50000
#define BROWS 256
#define CHW   3072
#define BK    64
#define PITCH 72          // 64 + 8 pad elements; 144B rows (16B aligned, bank-spread)
#define G1_BN 128
#define G2_BN 128
#define KCHUNK 6272       // 98 * 64, split-K chunk for GEMM2
#define NSPLIT 8

// ---------------- scalars from t ----------------
__global__ void k_scalars(const float* __restrict__ t, float* __restrict__ sc) {
    if (threadIdx.x == 0) {
        double tv  = (double)t[0];
        double ang = tv * (1.5707963267948966 / 1.008);
        double c   = cos(ang);
        double at  = c;              // sqrt(1-sched) = cos(ang), ang in (0, pi/2)
        double bt2 = 1.0 - c * c;    // sched
        sc[0] = (float)at;
        sc[1] = (float)bt2;
        sc[2] = (float)(at / bt2);             // c_cross  (coeff of cross in logits)
        sc[3] = (float)(0.5 / bt2);            // c_x2
        sc[4] = (float)(at * at * 0.5 / bt2);  // c_y2
        sc[5] = (float)(1.0 / bt2);            // inv_bt2
    }
}

// ---------------- x -> f16, x2 ----------------
__global__ void k_xprep(const float* __restrict__ x, _Float16* __restrict__ xh,
                        float* __restrict__ x2) {
    int row = blockIdx.x;
    int tid = threadIdx.x;
    const f32x4* xr = (const f32x4*)(x + (size_t)row * CHW);
    f16x4* xhr = (f16x4*)(xh + (size_t)row * CHW);
    float s = 0.f;
    for (int i = tid; i < CHW / 4; i += 256) {
        f32x4 v = xr[i];
        s += v[0]*v[0] + v[1]*v[1] + v[2]*v[2] + v[3]*v[3];
        f16x4 h;
        h[0] = (_Float16)v[0]; h[1] = (_Float16)v[1];
        h[2] = (_Float16)v[2]; h[3] = (_Float16)v[3];
        xhr[i] = h;
    }
    for (int o = 32; o > 0; o >>= 1) s += __shfl_down(s, o);
    __shared__ float wsum[4];
    if ((tid & 63) == 0) wsum[tid >> 6] = s;
    __syncthreads();
    if (tid == 0) x2[row] = (wsum[0] + wsum[1]) + (wsum[2] + wsum[3]);
}

// ---------------- GEMM1: logits = c_cross*(x@yT) - c_x2*x2 - c_y2*y2 ----------------
// BM=256 (all rows, images read once), BN=128, BK=64, 8 waves, 64x64 wave tiles,
// mfma_f32_32x32x16_f16. y2 folded into staging.
__global__ __launch_bounds__(512) void k_gemm1(
        const _Float16* __restrict__ xh, const float* __restrict__ img,
        const float* __restrict__ x2g, const float* __restrict__ sc,
        float* __restrict__ logits) {
    __shared__ _Float16 Alds[BROWS * PITCH];   // 36 KB
    __shared__ _Float16 Blds[G1_BN * PITCH];   // 18 KB
    __shared__ float y2lds[G1_BN];
    __shared__ float x2lds[BROWS];

    const int tid = threadIdx.x;
    const int n0  = blockIdx.x * G1_BN;
    if (tid < BROWS) x2lds[tid] = x2g[tid];

    // staging roles
    const int arow = tid >> 1;           // 0..255
    const int akk  = (tid & 1) * 32;     // 0/32
    const int brow = tid >> 2;           // 0..127
    const int bkk  = (tid & 3) * 16;     // 0..48
    const bool bvalid = (n0 + brow) < N_IMG;
    const _Float16* asrc = xh + (size_t)arow * CHW + akk;
    const float*    bsrc = img + (size_t)(n0 + brow) * CHW + bkk;

    f16x8 areg[4];
    f32x4 breg[4];
    float y2p = 0.f;
    const f32x4 fz = {0.f, 0.f, 0.f, 0.f};

    auto loadT = [&](int kt) {
        const f16x8* ap = (const f16x8*)(asrc + kt);
        areg[0] = ap[0]; areg[1] = ap[1]; areg[2] = ap[2]; areg[3] = ap[3];
        if (bvalid) {
            const f32x4* bp = (const f32x4*)(bsrc + kt);
            breg[0] = bp[0]; breg[1] = bp[1]; breg[2] = bp[2]; breg[3] = bp[3];
        } else {
            breg[0] = fz; breg[1] = fz; breg[2] = fz; breg[3] = fz;
        }
        #pragma unroll
        for (int i = 0; i < 4; i++)
            y2p += breg[i][0]*breg[i][0] + breg[i][1]*breg[i][1]
                 + breg[i][2]*breg[i][2] + breg[i][3]*breg[i][3];
    };
    auto storeT = [&]() {
        f16x8* adst = (f16x8*)&Alds[arow * PITCH + akk];
        adst[0] = areg[0]; adst[1] = areg[1]; adst[2] = areg[2]; adst[3] = areg[3];
        f16x8 b0, b1;
        #pragma unroll
        for (int j = 0; j < 4; j++) {
            b0[j]   = (_Float16)breg[0][j];
            b0[4+j] = (_Float16)breg[1][j];
            b1[j]   = (_Float16)breg[2][j];
            b1[4+j] = (_Float16)breg[3][j];
        }
        f16x8* bdst = (f16x8*)&Blds[brow * PITCH + bkk];
        bdst[0] = b0; bdst[1] = b1;
    };

    const int wid  = tid >> 6;
    const int lane = tid & 63;
    const int wm = wid >> 1, wn = wid & 1;
    const int rm = wm * 64, cn = wn * 64;
    const int lr = lane & 31, hi = lane >> 5;

    f32x16 acc[2][2];
    #pragma unroll
    for (int mi = 0; mi < 2; mi++)
        #pragma unroll
        for (int ni = 0; ni < 2; ni++)
            #pragma unroll
            for (int r = 0; r < 16; r++) acc[mi][ni][r] = 0.f;

    loadT(0);
    for (int it = 0; it < CHW / BK; ++it) {
        __syncthreads();
        storeT();
        __syncthreads();
        if (it + 1 < CHW / BK) loadT((it + 1) * BK);
        #pragma unroll
        for (int ks = 0; ks < 4; ++ks) {
            f16x8 a0 = *(const f16x8*)&Alds[(rm +      lr) * PITCH + ks*16 + hi*8];
            f16x8 a1 = *(const f16x8*)&Alds[(rm + 32 + lr) * PITCH + ks*16 + hi*8];
            f16x8 b0 = *(const f16x8*)&Blds[(cn +      lr) * PITCH + ks*16 + hi*8];
            f16x8 b1 = *(const f16x8*)&Blds[(cn + 32 + lr) * PITCH + ks*16 + hi*8];
            acc[0][0] = __builtin_amdgcn_mfma_f32_32x32x16_f16(a0, b0, acc[0][0], 0, 0, 0);
            acc[0][1] = __builtin_amdgcn_mfma_f32_32x32x16_f16(a0, b1, acc[0][1], 0, 0, 0);
            acc[1][0] = __builtin_amdgcn_mfma_f32_32x32x16_f16(a1, b0, acc[1][0], 0, 0, 0);
            acc[1][1] = __builtin_amdgcn_mfma_f32_32x32x16_f16(a1, b1, acc[1][1], 0, 0, 0);
        }
    }

    // fold y2 partials (4 threads per image row, consecutive lanes)
    float s = y2p;
    s += __shfl_xor(s, 1);
    s += __shfl_xor(s, 2);
    if ((tid & 3) == 0) y2lds[brow] = s;
    __syncthreads();

    const float c_cross = sc[2], c_x2 = sc[3], c_y2 = sc[4];
    #pragma unroll
    for (int mi = 0; mi < 2; mi++)
        #pragma unroll
        for (int ni = 0; ni < 2; ni++) {
            int col = n0 + cn + ni * 32 + lr;
            if (col >= N_IMG) continue;
            float y2v = y2lds[cn + ni * 32 + lr];
            f32x16 v = acc[mi][ni];
            #pragma unroll
            for (int r = 0; r < 16; r++) {
                int row = rm + mi * 32 + (r & 3) + 8 * (r >> 2) + 4 * hi;
                logits[(size_t)row * N_IMG + col] =
                    c_cross * v[r] - c_x2 * x2lds[row] - c_y2 * y2v;
            }
        }
}

// ---------------- row max ----------------
__global__ void k_rowmax(const float* __restrict__ logits, float* __restrict__ rmax) {
    int row = blockIdx.x, tid = threadIdx.x;
    const f32x4* lr = (const f32x4*)(logits + (size_t)row * N_IMG);
    float m = -3.0e38f;
    for (int i = tid; i < N_IMG / 4; i += 256) {
        f32x4 v = lr[i];
        m = fmaxf(m, fmaxf(fmaxf(v[0], v[1]), fmaxf(v[2], v[3])));
    }
    for (int o = 32; o > 0; o >>= 1) m = fmaxf(m, __shfl_down(m, o));
    __shared__ float wm4[4];
    if ((tid & 63) == 0) wm4[tid >> 6] = m;
    __syncthreads();
    if (tid == 0) rmax[row] = fmaxf(fmaxf(wm4[0], wm4[1]), fmaxf(wm4[2], wm4[3]));
}

// ---------------- exp + row sum, unnormalized p in f16 ----------------
__global__ void k_expsum(const float* __restrict__ logits, const float* __restrict__ rmax,
                         _Float16* __restrict__ eh, float* __restrict__ rowsum) {
    int row = blockIdx.x, tid = threadIdx.x;
    const f32x4* lr = (const f32x4*)(logits + (size_t)row * N_IMG);
    f16x4* er = (f16x4*)(eh + (size_t)row * N_IMG);
    float m = rmax[row], s = 0.f;
    for (int i = tid; i < N_IMG / 4; i += 256) {
        f32x4 v = lr[i];
        float e0 = __expf(v[0] - m), e1 = __expf(v[1] - m);
        float e2 = __expf(v[2] - m), e3 = __expf(v[3] - m);
        s += (e0 + e1) + (e2 + e3);
        f16x4 h;
        h[0] = (_Float16)e0; h[1] = (_Float16)e1;
        h[2] = (_Float16)e2; h[3] = (_Float16)e3;
        er[i] = h;
    }
    for (int o = 32; o > 0; o >>= 1) s += __shfl_down(s, o);
    __shared__ float ws4[4];
    if ((tid & 63) == 0) ws4[tid >> 6] = s;
    __syncthreads();
    if (tid == 0) rowsum[row] = (ws4[0] + ws4[1]) + (ws4[2] + ws4[3]);
}

// ---------------- GEMM2: partial[c] = eh[:, kchunk] @ img[kchunk, :] ----------------
__global__ __launch_bounds__(512) void k_gemm2(
        const _Float16* __restrict__ eh, const float* __restrict__ img,
        float* __restrict__ partial) {
    __shared__ _Float16 Alds[BROWS * PITCH];
    __shared__ _Float16 Blds[G2_BN * PITCH];

    const int tid = threadIdx.x;
    const int d0  = blockIdx.x * G2_BN;
    const int ck  = blockIdx.y;
    const int kbase = ck * KCHUNK;
    const int kend  = (kbase + KCHUNK < N_IMG) ? (kbase + KCHUNK) : N_IMG;
    const int iters = (kend - kbase + BK - 1) / BK;

    const int arow = tid >> 1;
    const int akk  = (tid & 1) * 32;
    const _Float16* asrc = eh + (size_t)arow * N_IMG + akk;
    const int bd = (tid & 31) * 4;    // d offset within tile
    const int bq = (tid >> 5) * 4;    // k offset within tile

    f16x8 areg[4];
    f32x4 breg[4];
    const f16x8 hz = {(_Float16)0.f,(_Float16)0.f,(_Float16)0.f,(_Float16)0.f,
                      (_Float16)0.f,(_Float16)0.f,(_Float16)0.f,(_Float16)0.f};
    const f32x4 fz = {0.f, 0.f, 0.f, 0.f};

    auto loadT = [&](int kt) {   // kt = absolute k of tile start
        #pragma unroll
        for (int j = 0; j < 4; j++) {
            int gk = kt + akk + j * 8;   // multiples of 8; 50000 % 8 == 0
            areg[j] = (gk < N_IMG) ? *(const f16x8*)(asrc + kt + j * 8) : hz;
        }
        #pragma unroll
        for (int i = 0; i < 4; i++) {
            int gk = kt + bq + i;
            breg[i] = (gk < N_IMG) ? *(const f32x4*)(img + (size_t)gk * CHW + d0 + bd) : fz;
        }
    };
    auto storeT = [&]() {
        f16x8* adst = (f16x8*)&Alds[arow * PITCH + akk];
        adst[0] = areg[0]; adst[1] = areg[1]; adst[2] = areg[2]; adst[3] = areg[3];
        #pragma unroll
        for (int j = 0; j < 4; j++) {   // transpose 4x4: k-runs per d column
            f16x4 h;
            h[0] = (_Float16)breg[0][j]; h[1] = (_Float16)breg[1][j];
            h[2] = (_Float16)breg[2][j]; h[3] = (_Float16)breg[3][j];
            *(f16x4*)&Blds[(bd + j) * PITCH + bq] = h;
        }
    };

    const int wid  = tid >> 6;
    const int lane = tid & 63;
    const int wm = wid >> 1, wn = wid & 1;
    const int rm = wm * 64, cn = wn * 64;
    const int lr = lane & 31, hi = lane >> 5;

    f32x16 acc[2][2];
    #pragma unroll
    for (int mi = 0; mi < 2; mi++)
        #pragma unroll
        for (int ni = 0; ni < 2; ni++)
            #pragma unroll
            for (int r = 0; r < 16; r++) acc[mi][ni][r] = 0.f;

    loadT(kbase);
    for (int it = 0; it < iters; ++it) {
        __syncthreads();
        storeT();
        __syncthreads();
        if (it + 1 < iters) loadT(kbase + (it + 1) * BK);
        #pragma unroll
        for (int ks = 0; ks < 4; ++ks) {
            f16x8 a0 = *(const f16x8*)&Alds[(rm +      lr) * PITCH + ks*16 + hi*8];
            f16x8 a1 = *(const f16x8*)&Alds[(rm + 32 + lr) * PITCH + ks*16 + hi*8];
            f16x8 b0 = *(const f16x8*)&Blds[(cn +      lr) * PITCH + ks*16 + hi*8];
            f16x8 b1 = *(const f16x8*)&Blds[(cn + 32 + lr) * PITCH + ks*16 + hi*8];
            acc[0][0] = __builtin_amdgcn_mfma_f32_32x32x16_f16(a0, b0, acc[0][0], 0, 0, 0);
            acc[0][1] = __builtin_amdgcn_mfma_f32_32x32x16_f16(a0, b1, acc[0][1], 0, 0, 0);
            acc[1][0] = __builtin_amdgcn_mfma_f32_32x32x16_f16(a1, b0, acc[1][0], 0, 0, 0);
            acc[1][1] = __builtin_amdgcn_mfma_f32_32x32x16_f16(a1, b1, acc[1][1], 0, 0, 0);
        }
    }

    float* pp = partial + (size_t)ck * BROWS * CHW;
    #pragma unroll
    for (int mi = 0; mi < 2; mi++)
        #pragma unroll
        for (int ni = 0; ni < 2; ni++) {
            int dcol = d0 + cn + ni * 32 + lr;
            f32x16 v = acc[mi][ni];
            #pragma unroll
            for (int r = 0; r < 16; r++) {
                int row = rm + mi * 32 + (r & 3) + 8 * (r >> 2) + 4 * hi;
                pp[(size_t)row * CHW + dcol] = v[r];
            }
        }
}

// ---------------- reduce partials + final score ----------------
__global__ void k_final(const float* __restrict__ partial, const float* __restrict__ x,
                        const float* __restrict__ rowsum, const float* __restrict__ sc,
                        float* __restrict__ out) {
    int idx = blockIdx.x * 256 + threadIdx.x;   // vec4 index; 196608 total
    int row = idx / (CHW / 4);
    float at = sc[0], invbt2 = sc[5];
    float scale = at * invbt2 / rowsum[row];
    const f32x4* p4 = (const f32x4*)partial;
    f32x4 s = p4[idx];
    #pragma unroll
    for (int c = 1; c < NSPLIT; c++) s = s + p4[(size_t)c * (BROWS * CHW / 4) + idx];
    f32x4 xv = ((const f32x4*)x)[idx];
    f32x4 o;
    #pragma unroll
    for (int j = 0; j < 4; j++) o[j] = s[j] * scale - xv[j] * invbt2;
    ((f32x4*)out)[idx] = o;
}

extern "C" void kernel_launch(void* const* d_in, const int* in_sizes, int n_in,
                              void* d_out, int out_size, void* d_ws, size_t ws_size,
                              hipStream_t stream) {
    const float* t   = (const float*)d_in[0];
    const float* x   = (const float*)d_in[1];
    const float* img = (const float*)d_in[2];
    float* out = (float*)d_out;
    char* ws = (char*)d_ws;

    // ws layout (bytes):
    float*    sc     = (float*)(ws + 0);                       // 64 B
    float*    x2     = (float*)(ws + 256);                     // 1 KB
    float*    rmax   = (float*)(ws + 1536);                    // 1 KB
    float*    rowsum = (float*)(ws + 2560);                    // 1 KB
    _Float16* xh     = (_Float16*)(ws + 4096);                 // 1.5 MB
    _Float16* eh     = (_Float16*)(ws + 4096 + 1572864);       // 25.6 MB
    float*    logits = (float*)(ws + 4096 + 1572864 + 25600000); // 51.2 MB
    float*    partial = logits;  // dead after k_expsum; reused (needs 25.2 MB)

    k_scalars<<<1, 64, 0, stream>>>(t, sc);
    k_xprep<<<256, 256, 0, stream>>>(x, xh, x2);
    k_gemm1<<<(N_IMG + G1_BN - 1) / G1_BN, 512, 0, stream>>>(xh, img, x2, sc, logits);
    k_rowmax<<<256, 256, 0, stream>>>(logits, rmax);
    k_expsum<<<256, 256, 0, stream>>>(logits, rmax, eh, rowsum);
    k_gemm2<<<dim3(CHW / G2_BN, NSPLIT), 512, 0, stream>>>(eh, img, partial);
    k_final<<<(BROWS * CHW / 4) / 256, 256, 0, stream>>>(partial, x, rowsum, sc, out);
}

// Round 3
// 566.594 us; speedup vs baseline: 1.1117x; 1.1117x over previous
//
#include <hip/hip_runtime.h>

typedef float    f32x4  __attribute__((ext_vector_type(4)));
typedef float    f32x16 __attribute__((ext_vector_type(16)));
typedef _Float16 f16x4  __attribute__((ext_vector_type(4)));
typedef _Float16 f16x8  __attribute__((ext_vector_type(8)));

#define N_IMG 50000
#define BROWS 256
#define CHW   3072
#define BK    32
#define PITCH 40          // 32 + 8 pad f16; 80B rows (16B-aligned)
#define BN    128
#define BM    128
#define KCHUNK 3136       // 98*32, split-K chunk for GEMM2
#define NSPLIT 16

// ---------------- scalars from t ----------------
__global__ void k_scalars(const float* __restrict__ t, float* __restrict__ sc) {
    if (threadIdx.x == 0) {
        double tv  = (double)t[0];
        double ang = tv * (1.5707963267948966 / 1.008);
        double c   = cos(ang);
        double at  = c;              // sqrt(1-sched) = cos(ang)
        double bt2 = 1.0 - c * c;    // sched
        sc[0] = (float)at;
        sc[1] = (float)bt2;
        sc[2] = (float)(at / bt2);             // c_cross
        sc[3] = (float)(at * at * 0.5 / bt2);  // c_y2
        sc[4] = (float)(1.0 / bt2);            // inv_bt2
    }
}

// ---------------- x -> f16 ----------------
// NOTE: the -||x||^2/(2 bt^2) logit term is a per-row constant -> exactly
// cancelled by the row-softmax (we subtract the row max of OUR logits).
// It is deliberately omitted everywhere.
__global__ void k_xprep(const float* __restrict__ x, _Float16* __restrict__ xh) {
    int idx = blockIdx.x * 256 + threadIdx.x;   // vec4 index over 256*3072/4
    f32x4 v = ((const f32x4*)x)[idx];
    f16x4 h;
    h[0] = (_Float16)v[0]; h[1] = (_Float16)v[1];
    h[2] = (_Float16)v[2]; h[3] = (_Float16)v[3];
    ((f16x4*)xh)[idx] = h;
}

// ---------------- GEMM1: logits = c_cross*(x@yT) - c_y2*y2 ----------------
// 128x128 tile, BK=32, 256 threads (4 waves, 2x2 of 64x64), ~4 blocks/CU.
// grid.x = mt (2, fastest: img-slab partners dispatch-adjacent), grid.y = n-tile.
__global__ __launch_bounds__(256, 4) void k_gemm1(
        const _Float16* __restrict__ xh, const float* __restrict__ img,
        const float* __restrict__ sc, float* __restrict__ logits) {
    __shared__ _Float16 Alds[BM * PITCH];   // 10 KB
    __shared__ _Float16 Blds[BN * PITCH];   // 10 KB
    __shared__ float y2lds[BN];

    const int tid = threadIdx.x;
    const int m0  = blockIdx.x * BM;
    const int n0  = blockIdx.y * BN;

    // staging roles
    const int arow = tid >> 1;            // 0..127
    const int akk  = (tid & 1) * 16;      // 0/16
    const int brow = tid >> 1;            // 0..127
    const int bkk  = (tid & 1) * 16;
    const bool bvalid = (n0 + brow) < N_IMG;
    const _Float16* asrc = xh + (size_t)(m0 + arow) * CHW + akk;
    const float*    bsrc = img + (size_t)(n0 + brow) * CHW + bkk;

    f16x8 areg[2];
    f32x4 breg[4];
    float y2p = 0.f;
    const f32x4 fz = {0.f, 0.f, 0.f, 0.f};

    auto loadT = [&](int kt) {
        const f16x8* ap = (const f16x8*)(asrc + kt);
        areg[0] = ap[0]; areg[1] = ap[1];
        if (bvalid) {
            const f32x4* bp = (const f32x4*)(bsrc + kt);
            breg[0] = bp[0]; breg[1] = bp[1]; breg[2] = bp[2]; breg[3] = bp[3];
        } else {
            breg[0] = fz; breg[1] = fz; breg[2] = fz; breg[3] = fz;
        }
        #pragma unroll
        for (int i = 0; i < 4; i++)
            y2p += breg[i][0]*breg[i][0] + breg[i][1]*breg[i][1]
                 + breg[i][2]*breg[i][2] + breg[i][3]*breg[i][3];
    };
    auto storeT = [&]() {
        f16x8* adst = (f16x8*)&Alds[arow * PITCH + akk];
        adst[0] = areg[0]; adst[1] = areg[1];
        f16x8 b0, b1;
        #pragma unroll
        for (int j = 0; j < 4; j++) {
            b0[j]   = (_Float16)breg[0][j];
            b0[4+j] = (_Float16)breg[1][j];
            b1[j]   = (_Float16)breg[2][j];
            b1[4+j] = (_Float16)breg[3][j];
        }
        f16x8* bdst = (f16x8*)&Blds[brow * PITCH + bkk];
        bdst[0] = b0; bdst[1] = b1;
    };

    const int wid  = tid >> 6;
    const int lane = tid & 63;
    const int wm = wid >> 1, wn = wid & 1;
    const int rm = wm * 64, cn = wn * 64;
    const int lr = lane & 31, hi = lane >> 5;

    f32x16 acc[2][2];
    #pragma unroll
    for (int mi = 0; mi < 2; mi++)
        #pragma unroll
        for (int ni = 0; ni < 2; ni++)
            #pragma unroll
            for (int r = 0; r < 16; r++) acc[mi][ni][r] = 0.f;

    loadT(0);
    for (int it = 0; it < CHW / BK; ++it) {
        __syncthreads();
        storeT();
        __syncthreads();
        if (it + 1 < CHW / BK) loadT((it + 1) * BK);
        #pragma unroll
        for (int ks = 0; ks < 2; ++ks) {
            f16x8 a0 = *(const f16x8*)&Alds[(rm +      lr) * PITCH + ks*16 + hi*8];
            f16x8 a1 = *(const f16x8*)&Alds[(rm + 32 + lr) * PITCH + ks*16 + hi*8];
            f16x8 b0 = *(const f16x8*)&Blds[(cn +      lr) * PITCH + ks*16 + hi*8];
            f16x8 b1 = *(const f16x8*)&Blds[(cn + 32 + lr) * PITCH + ks*16 + hi*8];
            acc[0][0] = __builtin_amdgcn_mfma_f32_32x32x16_f16(a0, b0, acc[0][0], 0, 0, 0);
            acc[0][1] = __builtin_amdgcn_mfma_f32_32x32x16_f16(a0, b1, acc[0][1], 0, 0, 0);
            acc[1][0] = __builtin_amdgcn_mfma_f32_32x32x16_f16(a1, b0, acc[1][0], 0, 0, 0);
            acc[1][1] = __builtin_amdgcn_mfma_f32_32x32x16_f16(a1, b1, acc[1][1], 0, 0, 0);
        }
    }

    // fold y2 partials (2 threads per image row)
    float s = y2p;
    s += __shfl_xor(s, 1);
    if ((tid & 1) == 0) y2lds[brow] = s;
    __syncthreads();

    const float c_cross = sc[2], c_y2 = sc[3];
    #pragma unroll
    for (int mi = 0; mi < 2; mi++)
        #pragma unroll
        for (int ni = 0; ni < 2; ni++) {
            int col = n0 + cn + ni * 32 + lr;
            if (col >= N_IMG) continue;
            float y2v = y2lds[cn + ni * 32 + lr];
            f32x16 v = acc[mi][ni];
            #pragma unroll
            for (int r = 0; r < 16; r++) {
                int row = m0 + rm + mi * 32 + (r & 3) + 8 * (r >> 2) + 4 * hi;
                logits[(size_t)row * N_IMG + col] = c_cross * v[r] - c_y2 * y2v;
            }
        }
}

// ---------------- fused row max + exp + row sum ----------------
__global__ void k_softmax(const float* __restrict__ logits, _Float16* __restrict__ eh,
                          float* __restrict__ rowsum) {
    int row = blockIdx.x, tid = threadIdx.x;
    const f32x4* lr = (const f32x4*)(logits + (size_t)row * N_IMG);
    f16x4* er = (f16x4*)(eh + (size_t)row * N_IMG);
    __shared__ float wred[4];

    float m = -3.0e38f;
    for (int i = tid; i < N_IMG / 4; i += 256) {
        f32x4 v = lr[i];
        m = fmaxf(m, fmaxf(fmaxf(v[0], v[1]), fmaxf(v[2], v[3])));
    }
    for (int o = 32; o > 0; o >>= 1) m = fmaxf(m, __shfl_down(m, o));
    if ((tid & 63) == 0) wred[tid >> 6] = m;
    __syncthreads();
    m = fmaxf(fmaxf(wred[0], wred[1]), fmaxf(wred[2], wred[3]));
    __syncthreads();

    float s = 0.f;
    for (int i = tid; i < N_IMG / 4; i += 256) {   // L2-hot second pass
        f32x4 v = lr[i];
        float e0 = __expf(v[0] - m), e1 = __expf(v[1] - m);
        float e2 = __expf(v[2] - m), e3 = __expf(v[3] - m);
        s += (e0 + e1) + (e2 + e3);
        f16x4 h;
        h[0] = (_Float16)e0; h[1] = (_Float16)e1;
        h[2] = (_Float16)e2; h[3] = (_Float16)e3;
        er[i] = h;
    }
    for (int o = 32; o > 0; o >>= 1) s += __shfl_down(s, o);
    if ((tid & 63) == 0) wred[tid >> 6] = s;
    __syncthreads();
    if (tid == 0) rowsum[row] = (wred[0] + wred[1]) + (wred[2] + wred[3]);
}

// ---------------- GEMM2: partial[ck] = eh[:, kchunk] @ img[kchunk, :] ----------------
// 128x128 tile, BK=32, 256 threads, grid (mt=2, dtile=24, ck=16) = 768 blocks.
__global__ __launch_bounds__(256, 4) void k_gemm2(
        const _Float16* __restrict__ eh, const float* __restrict__ img,
        float* __restrict__ partial) {
    __shared__ _Float16 Alds[BM * PITCH];
    __shared__ _Float16 Blds[BN * PITCH];

    const int tid = threadIdx.x;
    const int m0  = blockIdx.x * BM;
    const int d0  = blockIdx.y * BN;
    const int ck  = blockIdx.z;
    const int kbase = ck * KCHUNK;
    const int kend  = (kbase + KCHUNK < N_IMG) ? (kbase + KCHUNK) : N_IMG;
    const int iters = (kend - kbase + BK - 1) / BK;

    const int arow = tid >> 1;
    const int akk  = (tid & 1) * 16;
    const _Float16* asrc = eh + (size_t)(m0 + arow) * N_IMG + akk;
    const int bd = (tid & 31) * 4;    // d offset within tile
    const int bq = (tid >> 5) * 4;    // k offset within tile (0..28)

    f16x8 areg[2];
    f32x4 breg[4];
    const f16x8 hz = {(_Float16)0.f,(_Float16)0.f,(_Float16)0.f,(_Float16)0.f,
                      (_Float16)0.f,(_Float16)0.f,(_Float16)0.f,(_Float16)0.f};
    const f32x4 fz = {0.f, 0.f, 0.f, 0.f};

    auto loadT = [&](int kt) {   // kt = absolute k of tile start
        #pragma unroll
        for (int j = 0; j < 2; j++) {
            int gk = kt + akk + j * 8;   // multiples of 8; 50000 % 8 == 0
            areg[j] = (gk < N_IMG) ? *(const f16x8*)(asrc + kt + j * 8) : hz;
        }
        #pragma unroll
        for (int i = 0; i < 4; i++) {
            int gk = kt + bq + i;
            breg[i] = (gk < N_IMG) ? *(const f32x4*)(img + (size_t)gk * CHW + d0 + bd) : fz;
        }
    };
    auto storeT = [&]() {
        f16x8* adst = (f16x8*)&Alds[arow * PITCH + akk];
        adst[0] = areg[0]; adst[1] = areg[1];
        #pragma unroll
        for (int j = 0; j < 4; j++) {   // transpose 4x4: k-runs per d column
            f16x4 h;
            h[0] = (_Float16)breg[0][j]; h[1] = (_Float16)breg[1][j];
            h[2] = (_Float16)breg[2][j]; h[3] = (_Float16)breg[3][j];
            *(f16x4*)&Blds[(bd + j) * PITCH + bq] = h;
        }
    };

    const int wid  = tid >> 6;
    const int lane = tid & 63;
    const int wm = wid >> 1, wn = wid & 1;
    const int rm = wm * 64, cn = wn * 64;
    const int lr = lane & 31, hi = lane >> 5;

    f32x16 acc[2][2];
    #pragma unroll
    for (int mi = 0; mi < 2; mi++)
        #pragma unroll
        for (int ni = 0; ni < 2; ni++)
            #pragma unroll
            for (int r = 0; r < 16; r++) acc[mi][ni][r] = 0.f;

    loadT(kbase);
    for (int it = 0; it < iters; ++it) {
        __syncthreads();
        storeT();
        __syncthreads();
        if (it + 1 < iters) loadT(kbase + (it + 1) * BK);
        #pragma unroll
        for (int ks = 0; ks < 2; ++ks) {
            f16x8 a0 = *(const f16x8*)&Alds[(rm +      lr) * PITCH + ks*16 + hi*8];
            f16x8 a1 = *(const f16x8*)&Alds[(rm + 32 + lr) * PITCH + ks*16 + hi*8];
            f16x8 b0 = *(const f16x8*)&Blds[(cn +      lr) * PITCH + ks*16 + hi*8];
            f16x8 b1 = *(const f16x8*)&Blds[(cn + 32 + lr) * PITCH + ks*16 + hi*8];
            acc[0][0] = __builtin_amdgcn_mfma_f32_32x32x16_f16(a0, b0, acc[0][0], 0, 0, 0);
            acc[0][1] = __builtin_amdgcn_mfma_f32_32x32x16_f16(a0, b1, acc[0][1], 0, 0, 0);
            acc[1][0] = __builtin_amdgcn_mfma_f32_32x32x16_f16(a1, b0, acc[1][0], 0, 0, 0);
            acc[1][1] = __builtin_amdgcn_mfma_f32_32x32x16_f16(a1, b1, acc[1][1], 0, 0, 0);
        }
    }

    float* pp = partial + (size_t)ck * BROWS * CHW;
    #pragma unroll
    for (int mi = 0; mi < 2; mi++)
        #pragma unroll
        for (int ni = 0; ni < 2; ni++) {
            int dcol = d0 + cn + ni * 32 + lr;
            f32x16 v = acc[mi][ni];
            #pragma unroll
            for (int r = 0; r < 16; r++) {
                int row = m0 + rm + mi * 32 + (r & 3) + 8 * (r >> 2) + 4 * hi;
                pp[(size_t)row * CHW + dcol] = v[r];
            }
        }
}

// ---------------- reduce partials + final score ----------------
__global__ void k_final(const float* __restrict__ partial, const float* __restrict__ x,
                        const float* __restrict__ rowsum, const float* __restrict__ sc,
                        float* __restrict__ out) {
    int idx = blockIdx.x * 256 + threadIdx.x;   // vec4 index; 196608 total
    int row = idx / (CHW / 4);
    float at = sc[0], invbt2 = sc[4];
    float scale = at * invbt2 / rowsum[row];
    const f32x4* p4 = (const f32x4*)partial;
    f32x4 s = p4[idx];
    #pragma unroll
    for (int c = 1; c < NSPLIT; c++) s = s + p4[(size_t)c * (BROWS * CHW / 4) + idx];
    f32x4 xv = ((const f32x4*)x)[idx];
    f32x4 o;
    #pragma unroll
    for (int j = 0; j < 4; j++) o[j] = s[j] * scale - xv[j] * invbt2;
    ((f32x4*)out)[idx] = o;
}

extern "C" void kernel_launch(void* const* d_in, const int* in_sizes, int n_in,
                              void* d_out, int out_size, void* d_ws, size_t ws_size,
                              hipStream_t stream) {
    const float* t   = (const float*)d_in[0];
    const float* x   = (const float*)d_in[1];
    const float* img = (const float*)d_in[2];
    float* out = (float*)d_out;
    char* ws = (char*)d_ws;

    // ws layout (bytes):
    float*    sc     = (float*)(ws + 0);                       // 64 B
    float*    rowsum = (float*)(ws + 2560);                    // 1 KB
    _Float16* xh     = (_Float16*)(ws + 4096);                 // 1.5 MB
    _Float16* eh     = (_Float16*)(ws + 4096 + 1572864);       // 25.6 MB
    float*    logits = (float*)(ws + 4096 + 1572864 + 25600000); // 51.2 MB
    float*    partial = logits;  // dead after k_softmax; reused (needs 50.4 MB)

    k_scalars<<<1, 64, 0, stream>>>(t, sc);
    k_xprep<<<(BROWS * CHW / 4) / 256, 256, 0, stream>>>(x, xh);
    k_gemm1<<<dim3(2, (N_IMG + BN - 1) / BN), 256, 0, stream>>>(xh, img, sc, logits);
    k_softmax<<<256, 256, 0, stream>>>(logits, eh, rowsum);
    k_gemm2<<<dim3(2, CHW / BN, NSPLIT), 256, 0, stream>>>(eh, img, partial);
    k_final<<<(BROWS * CHW / 4) / 256, 256, 0, stream>>>(partial, x, rowsum, sc, out);
}

// Round 4
// 490.298 us; speedup vs baseline: 1.2847x; 1.1556x over previous
//
#include <hip/hip_runtime.h>

typedef float    f32x4  __attribute__((ext_vector_type(4)));
typedef float    f32x16 __attribute__((ext_vector_type(16)));
typedef _Float16 f16x4  __attribute__((ext_vector_type(4)));
typedef _Float16 f16x8  __attribute__((ext_vector_type(8)));

#define N_IMG 50000
#define BROWS 256
#define CHW   3072
#define BK    64
#define BM    128
#define BN    128
#define EHS   50176       // padded eh row stride = 16*3136 (zeros beyond 50000)
#define KCHUNK 3136       // 49*64 split-K chunk for GEMM2
#define NSPLIT 16

// direct global->LDS (wave-uniform LDS base + lane*16B; per-lane global addr)
__device__ __forceinline__ void glds16(const void* g, void* l) {
    __builtin_amdgcn_global_load_lds(
        (const __attribute__((address_space(1))) void*)g,
        (__attribute__((address_space(3))) void*)l, 16, 0, 0);
}

// ---------------- scalars from t ----------------
__global__ void k_scalars(const float* __restrict__ t, float* __restrict__ sc) {
    if (threadIdx.x == 0) {
        double tv  = (double)t[0];
        double ang = tv * (1.5707963267948966 / 1.008);
        double c   = cos(ang);
        double at  = c;
        double bt2 = 1.0 - c * c;
        sc[0] = (float)at;
        sc[1] = (float)bt2;
        sc[2] = (float)(at / bt2);             // c_cross
        sc[3] = (float)(at * at * 0.5 / bt2);  // c_y2
        sc[4] = (float)(1.0 / bt2);            // inv_bt2
    }
}

// ---------------- x -> f16 ----------------
// -||x||^2 logit term is a per-row constant -> cancelled by row softmax; omitted.
__global__ void k_xprep(const float* __restrict__ x, _Float16* __restrict__ xh) {
    int idx = blockIdx.x * 256 + threadIdx.x;
    f32x4 v = ((const f32x4*)x)[idx];
    f16x4 h;
    h[0] = (_Float16)v[0]; h[1] = (_Float16)v[1];
    h[2] = (_Float16)v[2]; h[3] = (_Float16)v[3];
    ((f16x4*)xh)[idx] = h;
}

// ---------------- img -> f16 + y2 (one streaming pass) ----------------
__global__ void k_prep(const float* __restrict__ img, _Float16* __restrict__ imgh,
                       float* __restrict__ y2) {
    int row = blockIdx.x, tid = threadIdx.x;
    const f32x4* src = (const f32x4*)(img + (size_t)row * CHW);
    f16x4* dst = (f16x4*)(imgh + (size_t)row * CHW);
    float s = 0.f;
    #pragma unroll
    for (int i = 0; i < 3; i++) {
        f32x4 v = src[tid + i * 256];
        s += v[0]*v[0] + v[1]*v[1] + v[2]*v[2] + v[3]*v[3];
        f16x4 h;
        h[0] = (_Float16)v[0]; h[1] = (_Float16)v[1];
        h[2] = (_Float16)v[2]; h[3] = (_Float16)v[3];
        dst[tid + i * 256] = h;
    }
    for (int o = 32; o > 0; o >>= 1) s += __shfl_down(s, o);
    __shared__ float wsum[4];
    if ((tid & 63) == 0) wsum[tid >> 6] = s;
    __syncthreads();
    if (tid == 0) y2[row] = (wsum[0] + wsum[1]) + (wsum[2] + wsum[3]);
}

// ---------------- GEMM1: logits = c_cross*(xh@imghT) - c_y2*y2 ----------------
// m97 structure: 128x128x64, glds width16 both tiles, linear LDS + XOR swizzle,
// 4 waves (2x2 of 64x64), 32x32x16_f16.
__global__ __launch_bounds__(256, 3) void k_gemm1(
        const _Float16* __restrict__ xh, const _Float16* __restrict__ imgh,
        const float* __restrict__ y2g, const float* __restrict__ sc,
        float* __restrict__ logits) {
    __shared__ _Float16 Alds[BM * BK];   // 16 KB, [row][k] with granule XOR swizzle
    __shared__ _Float16 Blds[BN * BK];   // 16 KB

    const int tid = threadIdx.x;
    const int wid = tid >> 6, lane = tid & 63;
    const int m0 = blockIdx.x * BM;
    const int n0 = blockIdx.y * BN;

    // staging: 16 wave-issues per tile; issue seg covers rows seg*8..+8.
    // LDS slot (row, g) holds global k-granule g ^ (row&7)  (16B granules).
    const _Float16* gA[4]; const _Float16* gB[4];
    _Float16* lA[4]; _Float16* lB[4];
    #pragma unroll
    for (int j = 0; j < 4; j++) {
        int seg = wid * 4 + j;                       // 0..15
        int row = seg * 8 + (lane >> 3);             // 0..127
        int off = (((lane & 7) ^ (row & 7)) << 3);   // swizzled k-offset (f16 els)
        gA[j] = xh + (size_t)(m0 + row) * CHW + off;
        int rb = n0 + row; if (rb > N_IMG - 1) rb = N_IMG - 1;
        gB[j] = imgh + (size_t)rb * CHW + off;
        lA[j] = Alds + seg * 512;                    // 1024 B per issue
        lB[j] = Blds + seg * 512;
    }

    const int wm = wid >> 1, wn = wid & 1;
    const int rm = wm * 64, cn = wn * 64;
    const int lr = lane & 31, hi = lane >> 5;
    const int xm = (lr & 7) << 4;                    // read-side byte XOR
    const char* Ab = (const char*)Alds;
    const char* Bb = (const char*)Blds;
    const int ar0 = (rm + lr) * 128,      ar1 = (rm + 32 + lr) * 128;
    const int br0 = (cn + lr) * 128,      br1 = (cn + 32 + lr) * 128;
    const int kof = hi * 16;

    f32x16 acc[2][2];
    #pragma unroll
    for (int mi = 0; mi < 2; mi++)
        #pragma unroll
        for (int ni = 0; ni < 2; ni++)
            #pragma unroll
            for (int r = 0; r < 16; r++) acc[mi][ni][r] = 0.f;

    for (int it = 0; it < CHW / BK; ++it) {
        if (it) __syncthreads();                 // prior reads done
        #pragma unroll
        for (int j = 0; j < 4; j++) glds16(gA[j] + it * BK, lA[j]);
        #pragma unroll
        for (int j = 0; j < 4; j++) glds16(gB[j] + it * BK, lB[j]);
        __syncthreads();                         // vmcnt(0) drain + barrier
        #pragma unroll
        for (int ks = 0; ks < 4; ++ks) {
            int off = (ks * 32 + kof) ^ xm;
            f16x8 a0 = *(const f16x8*)(Ab + ar0 + off);
            f16x8 a1 = *(const f16x8*)(Ab + ar1 + off);
            f16x8 b0 = *(const f16x8*)(Bb + br0 + off);
            f16x8 b1 = *(const f16x8*)(Bb + br1 + off);
            acc[0][0] = __builtin_amdgcn_mfma_f32_32x32x16_f16(a0, b0, acc[0][0], 0, 0, 0);
            acc[0][1] = __builtin_amdgcn_mfma_f32_32x32x16_f16(a0, b1, acc[0][1], 0, 0, 0);
            acc[1][0] = __builtin_amdgcn_mfma_f32_32x32x16_f16(a1, b0, acc[1][0], 0, 0, 0);
            acc[1][1] = __builtin_amdgcn_mfma_f32_32x32x16_f16(a1, b1, acc[1][1], 0, 0, 0);
        }
    }

    const float c_cross = sc[2], c_y2 = sc[3];
    #pragma unroll
    for (int mi = 0; mi < 2; mi++)
        #pragma unroll
        for (int ni = 0; ni < 2; ni++) {
            int col = n0 + cn + ni * 32 + lr;
            if (col >= N_IMG) continue;
            float y2v = y2g[col];
            f32x16 v = acc[mi][ni];
            #pragma unroll
            for (int r = 0; r < 16; r++) {
                int row = m0 + rm + mi * 32 + (r & 3) + 8 * (r >> 2) + 4 * hi;
                logits[(size_t)row * N_IMG + col] = c_cross * v[r] - c_y2 * y2v;
            }
        }
}

// ---------------- fused row max + exp + row sum (writes padded eh) ----------------
__global__ void k_softmax(const float* __restrict__ logits, _Float16* __restrict__ eh,
                          float* __restrict__ rowsum) {
    int row = blockIdx.x, tid = threadIdx.x;
    const f32x4* lr = (const f32x4*)(logits + (size_t)row * N_IMG);
    _Float16* erow = eh + (size_t)row * EHS;
    f16x4* er = (f16x4*)erow;
    __shared__ float wred[4];

    if (tid < EHS - N_IMG) erow[N_IMG + tid] = (_Float16)0.f;   // zero K-tail pad

    float m = -3.0e38f;
    for (int i = tid; i < N_IMG / 4; i += 256) {
        f32x4 v = lr[i];
        m = fmaxf(m, fmaxf(fmaxf(v[0], v[1]), fmaxf(v[2], v[3])));
    }
    for (int o = 32; o > 0; o >>= 1) m = fmaxf(m, __shfl_down(m, o));
    if ((tid & 63) == 0) wred[tid >> 6] = m;
    __syncthreads();
    m = fmaxf(fmaxf(wred[0], wred[1]), fmaxf(wred[2], wred[3]));
    __syncthreads();

    float s = 0.f;
    for (int i = tid; i < N_IMG / 4; i += 256) {
        f32x4 v = lr[i];
        float e0 = __expf(v[0] - m), e1 = __expf(v[1] - m);
        float e2 = __expf(v[2] - m), e3 = __expf(v[3] - m);
        s += (e0 + e1) + (e2 + e3);
        f16x4 h;
        h[0] = (_Float16)e0; h[1] = (_Float16)e1;
        h[2] = (_Float16)e2; h[3] = (_Float16)e3;
        er[i] = h;
    }
    for (int o = 32; o > 0; o >>= 1) s += __shfl_down(s, o);
    if ((tid & 63) == 0) wred[tid >> 6] = s;
    __syncthreads();
    if (tid == 0) rowsum[row] = (wred[0] + wred[1]) + (wred[2] + wred[3]);
}

// ---------------- GEMM2: partial[ck] = eh[:,chunk] @ imgh[chunk,:] ----------------
// A (eh): glds + swizzle. B (imgh, k-strided): f16 reg-stage + 4x8 transpose
// into padded-pitch-72 LDS.
__global__ __launch_bounds__(256, 3) void k_gemm2(
        const _Float16* __restrict__ eh, const _Float16* __restrict__ imgh,
        float* __restrict__ partial) {
    __shared__ _Float16 Alds[BM * BK];     // [row][k] swizzled, 16 KB
    __shared__ _Float16 Blds[BN * 72];     // [d][k] pitch 72, 18 KB

    const int tid = threadIdx.x;
    const int wid = tid >> 6, lane = tid & 63;
    const int m0 = blockIdx.x * BM;
    const int d0 = blockIdx.y * BN;
    const int ck = blockIdx.z;
    const int kbase = ck * KCHUNK;
    const int kend  = (kbase + KCHUNK < N_IMG) ? (kbase + KCHUNK) : N_IMG;
    const int iters = (kend - kbase + BK - 1) / BK;

    // A staging (glds)
    const _Float16* gA[4]; _Float16* lA[4];
    #pragma unroll
    for (int j = 0; j < 4; j++) {
        int seg = wid * 4 + j;
        int row = seg * 8 + (lane >> 3);
        int off = (((lane & 7) ^ (row & 7)) << 3);
        gA[j] = eh + (size_t)(m0 + row) * EHS + kbase + off;
        lA[j] = Alds + seg * 512;
    }
    // B staging (reg transpose): thread covers 8 k-rows x 4 d
    const int bd = (tid & 31) * 4;
    const int bq = (tid >> 5) * 8;
    f16x4 breg[8];
    auto loadB = [&](int kt) {
        #pragma unroll
        for (int i = 0; i < 8; i++) {
            int k = kt + bq + i; if (k > N_IMG - 1) k = N_IMG - 1;  // dup rows: A pad=0
            breg[i] = *(const f16x4*)(imgh + (size_t)k * CHW + d0 + bd);
        }
    };
    auto storeB = [&]() {
        #pragma unroll
        for (int j = 0; j < 4; j++) {
            f16x8 w;
            #pragma unroll
            for (int i = 0; i < 8; i++) w[i] = breg[i][j];
            *(f16x8*)&Blds[(bd + j) * 72 + bq] = w;
        }
    };

    const int wm = wid >> 1, wn = wid & 1;
    const int rm = wm * 64, cn = wn * 64;
    const int lr = lane & 31, hi = lane >> 5;
    const int xm = (lr & 7) << 4;
    const char* Ab = (const char*)Alds;
    const int ar0 = (rm + lr) * 128, ar1 = (rm + 32 + lr) * 128;
    const int kof = hi * 16;

    f32x16 acc[2][2];
    #pragma unroll
    for (int mi = 0; mi < 2; mi++)
        #pragma unroll
        for (int ni = 0; ni < 2; ni++)
            #pragma unroll
            for (int r = 0; r < 16; r++) acc[mi][ni][r] = 0.f;

    loadB(kbase);
    for (int it = 0; it < iters; ++it) {
        if (it) __syncthreads();
        #pragma unroll
        for (int j = 0; j < 4; j++) glds16(gA[j] + it * BK, lA[j]);
        storeB();
        __syncthreads();
        if (it + 1 < iters) loadB(kbase + (it + 1) * BK);   // overlaps MFMA
        #pragma unroll
        for (int ks = 0; ks < 4; ++ks) {
            int offa = (ks * 32 + kof) ^ xm;
            int offb = ks * 16 + hi * 8;
            f16x8 a0 = *(const f16x8*)(Ab + ar0 + offa);
            f16x8 a1 = *(const f16x8*)(Ab + ar1 + offa);
            f16x8 b0 = *(const f16x8*)&Blds[(cn +      lr) * 72 + offb];
            f16x8 b1 = *(const f16x8*)&Blds[(cn + 32 + lr) * 72 + offb];
            acc[0][0] = __builtin_amdgcn_mfma_f32_32x32x16_f16(a0, b0, acc[0][0], 0, 0, 0);
            acc[0][1] = __builtin_amdgcn_mfma_f32_32x32x16_f16(a0, b1, acc[0][1], 0, 0, 0);
            acc[1][0] = __builtin_amdgcn_mfma_f32_32x32x16_f16(a1, b0, acc[1][0], 0, 0, 0);
            acc[1][1] = __builtin_amdgcn_mfma_f32_32x32x16_f16(a1, b1, acc[1][1], 0, 0, 0);
        }
    }

    float* pp = partial + (size_t)ck * BROWS * CHW;
    #pragma unroll
    for (int mi = 0; mi < 2; mi++)
        #pragma unroll
        for (int ni = 0; ni < 2; ni++) {
            int dcol = d0 + cn + ni * 32 + lr;
            f32x16 v = acc[mi][ni];
            #pragma unroll
            for (int r = 0; r < 16; r++) {
                int row = m0 + rm + mi * 32 + (r & 3) + 8 * (r >> 2) + 4 * hi;
                pp[(size_t)row * CHW + dcol] = v[r];
            }
        }
}

// ---------------- reduce partials + final score ----------------
__global__ void k_final(const float* __restrict__ partial, const float* __restrict__ x,
                        const float* __restrict__ rowsum, const float* __restrict__ sc,
                        float* __restrict__ out) {
    int idx = blockIdx.x * 256 + threadIdx.x;
    int row = idx / (CHW / 4);
    float at = sc[0], invbt2 = sc[4];
    float scale = at * invbt2 / rowsum[row];
    const f32x4* p4 = (const f32x4*)partial;
    f32x4 s = p4[idx];
    #pragma unroll
    for (int c = 1; c < NSPLIT; c++) s = s + p4[(size_t)c * (BROWS * CHW / 4) + idx];
    f32x4 xv = ((const f32x4*)x)[idx];
    f32x4 o;
    #pragma unroll
    for (int j = 0; j < 4; j++) o[j] = s[j] * scale - xv[j] * invbt2;
    ((f32x4*)out)[idx] = o;
}

extern "C" void kernel_launch(void* const* d_in, const int* in_sizes, int n_in,
                              void* d_out, int out_size, void* d_ws, size_t ws_size,
                              hipStream_t stream) {
    const float* t   = (const float*)d_in[0];
    const float* x   = (const float*)d_in[1];
    const float* img = (const float*)d_in[2];
    float* out = (float*)d_out;
    char* ws = (char*)d_ws;

    // ws layout (bytes)
    float*    sc     = (float*)(ws + 0);                  // 64 B
    float*    rowsum = (float*)(ws + 256);                // 1 KB
    float*    y2     = (float*)(ws + 4096);               // 200 KB
    _Float16* xh     = (_Float16*)(ws + 212992);          // 1.5 MB
    _Float16* imgh   = (_Float16*)(ws + 2097152);         // 307.2 MB
    _Float16* eh     = (_Float16*)(ws + 311427072);       // 25.7 MB (stride EHS)
    float*    logits = (float*)(ws + 337117184);          // 51.2 MB
    float*    partial = logits;                            // reused (50.4 MB)

    k_scalars<<<1, 64, 0, stream>>>(t, sc);
    k_xprep<<<(BROWS * CHW / 4) / 256, 256, 0, stream>>>(x, xh);
    k_prep<<<N_IMG, 256, 0, stream>>>(img, imgh, y2);
    k_gemm1<<<dim3(2, (N_IMG + BN - 1) / BN), 256, 0, stream>>>(xh, imgh, y2, sc, logits);
    k_softmax<<<256, 256, 0, stream>>>(logits, eh, rowsum);
    k_gemm2<<<dim3(2, CHW / BN, NSPLIT), 256, 0, stream>>>(eh, imgh, partial);
    k_final<<<(BROWS * CHW / 4) / 256, 256, 0, stream>>>(partial, x, rowsum, sc, out);
}

// Round 5
// 484.744 us; speedup vs baseline: 1.2994x; 1.0115x over previous
//
#include <hip/hip_runtime.h>

typedef float    f32x4  __attribute__((ext_vector_type(4)));
typedef float    f32x16 __attribute__((ext_vector_type(16)));
typedef _Float16 f16x4  __attribute__((ext_vector_type(4)));
typedef _Float16 f16x8  __attribute__((ext_vector_type(8)));

#define N_IMG 50000
#define BROWS 256
#define CHW   3072
#define BK    64
#define BM    128
#define BN    128
#define EHS   50176       // padded eh row stride = 16*3136 (zeros beyond 50000)
#define KCHUNK 3136       // 49*64 split-K chunk for GEMM2
#define NSPLIT 16

// direct global->LDS (wave-uniform LDS base + lane*16B; per-lane global addr)
__device__ __forceinline__ void glds16(const void* g, void* l) {
    __builtin_amdgcn_global_load_lds(
        (const __attribute__((address_space(1))) void*)g,
        (__attribute__((address_space(3))) void*)l, 16, 0, 0);
}

// ---------------- scalars from t ----------------
__global__ void k_scalars(const float* __restrict__ t, float* __restrict__ sc) {
    if (threadIdx.x == 0) {
        double tv  = (double)t[0];
        double ang = tv * (1.5707963267948966 / 1.008);
        double c   = cos(ang);
        double at  = c;
        double bt2 = 1.0 - c * c;
        sc[0] = (float)at;
        sc[1] = (float)bt2;
        sc[2] = (float)(at / bt2);             // c_cross
        sc[3] = (float)(at * at * 0.5 / bt2);  // c_y2
        sc[4] = (float)(1.0 / bt2);            // inv_bt2
    }
}

// ---------------- x -> f16 ----------------
// -||x||^2 logit term is a per-row constant -> cancelled by row softmax; omitted.
__global__ void k_xprep(const float* __restrict__ x, _Float16* __restrict__ xh) {
    int idx = blockIdx.x * 256 + threadIdx.x;
    f32x4 v = ((const f32x4*)x)[idx];
    f16x4 h;
    h[0] = (_Float16)v[0]; h[1] = (_Float16)v[1];
    h[2] = (_Float16)v[2]; h[3] = (_Float16)v[3];
    ((f16x4*)xh)[idx] = h;
}

// ---------------- GEMM1: logits = c_cross*(xh@imgT) - c_y2*y2 ----------------
// A: glds from xh (f16, LLC-resident). B: reg-staged from img f32, cvt->f16,
// XOR-swizzled ds_write (write map == read map). y2 folded into B staging.
__global__ __launch_bounds__(256, 3) void k_gemm1(
        const _Float16* __restrict__ xh, const float* __restrict__ img,
        const float* __restrict__ sc, float* __restrict__ logits) {
    __shared__ _Float16 Alds[BM * BK];   // 16 KB, [row][g^(row&7)] 16B granules
    __shared__ _Float16 Blds[BN * BK];   // 16 KB, same swizzle
    __shared__ float y2lds[BN];

    const int tid = threadIdx.x;
    const int wid = tid >> 6, lane = tid & 63;
    const int m0 = blockIdx.x * BM;
    const int n0 = blockIdx.y * BN;

    // A staging via glds: 16 wave-issues, seg covers rows seg*8..+8
    const _Float16* gA[4]; _Float16* lA[4];
    #pragma unroll
    for (int j = 0; j < 4; j++) {
        int seg = wid * 4 + j;
        int row = seg * 8 + (lane >> 3);
        int off = (((lane & 7) ^ (row & 7)) << 3);   // f16 elements
        gA[j] = xh + (size_t)(m0 + row) * CHW + off;
        lA[j] = Alds + seg * 512;
    }

    // B staging from f32: thread owns granule bg of rows brow+{0,32,64,96}
    const int brow = tid >> 3;          // 0..31
    const int bg   = tid & 7;           // k-granule (8 f32)
    const float* bsrc[4];
    #pragma unroll
    for (int i = 0; i < 4; i++) {
        int r = n0 + brow + 32 * i; if (r > N_IMG - 1) r = N_IMG - 1;
        bsrc[i] = img + (size_t)r * CHW + bg * 8;
    }
    const int bswz = ((bg ^ (brow & 7)) << 4);       // byte offset of granule
    f32x4 br[4][2];
    float y2p[4] = {0.f, 0.f, 0.f, 0.f};

    auto loadB = [&](int kt) {
        #pragma unroll
        for (int i = 0; i < 4; i++) {
            br[i][0] = *(const f32x4*)(bsrc[i] + kt);
            br[i][1] = *(const f32x4*)(bsrc[i] + kt + 4);
        }
    };
    auto storeB = [&]() {
        #pragma unroll
        for (int i = 0; i < 4; i++) {
            f16x8 h;
            #pragma unroll
            for (int j = 0; j < 4; j++) {
                float a = br[i][0][j], b = br[i][1][j];
                h[j] = (_Float16)a; h[4 + j] = (_Float16)b;
                y2p[i] += a * a + b * b;
            }
            *(f16x8*)((char*)Blds + (brow + 32 * i) * 128 + bswz) = h;
        }
    };

    const int wm = wid >> 1, wn = wid & 1;
    const int rm = wm * 64, cn = wn * 64;
    const int lr = lane & 31, hi = lane >> 5;
    const int xm = (lr & 7) << 4;                    // read-side byte XOR
    const char* Ab = (const char*)Alds;
    const char* Bb = (const char*)Blds;
    const int ar0 = (rm + lr) * 128,      ar1 = (rm + 32 + lr) * 128;
    const int br0 = (cn + lr) * 128,      br1 = (cn + 32 + lr) * 128;
    const int kof = hi * 16;

    f32x16 acc[2][2];
    #pragma unroll
    for (int mi = 0; mi < 2; mi++)
        #pragma unroll
        for (int ni = 0; ni < 2; ni++)
            #pragma unroll
            for (int r = 0; r < 16; r++) acc[mi][ni][r] = 0.f;

    loadB(0);
    for (int it = 0; it < CHW / BK; ++it) {
        if (it) __syncthreads();                 // prior reads done
        #pragma unroll
        for (int j = 0; j < 4; j++) glds16(gA[j] + it * BK, lA[j]);
        storeB();
        __syncthreads();                         // vmcnt/lgkm drain + barrier
        if (it + 1 < CHW / BK) loadB((it + 1) * BK);   // overlaps MFMA
        #pragma unroll
        for (int ks = 0; ks < 4; ++ks) {
            int off = (ks * 32 + kof) ^ xm;
            f16x8 a0 = *(const f16x8*)(Ab + ar0 + off);
            f16x8 a1 = *(const f16x8*)(Ab + ar1 + off);
            f16x8 b0 = *(const f16x8*)(Bb + br0 + off);
            f16x8 b1 = *(const f16x8*)(Bb + br1 + off);
            acc[0][0] = __builtin_amdgcn_mfma_f32_32x32x16_f16(a0, b0, acc[0][0], 0, 0, 0);
            acc[0][1] = __builtin_amdgcn_mfma_f32_32x32x16_f16(a0, b1, acc[0][1], 0, 0, 0);
            acc[1][0] = __builtin_amdgcn_mfma_f32_32x32x16_f16(a1, b0, acc[1][0], 0, 0, 0);
            acc[1][1] = __builtin_amdgcn_mfma_f32_32x32x16_f16(a1, b1, acc[1][1], 0, 0, 0);
        }
    }

    // y2 reduce: 8 lanes (same brow) hold disjoint k-granule partials
    #pragma unroll
    for (int i = 0; i < 4; i++) {
        float s = y2p[i];
        s += __shfl_xor(s, 1);
        s += __shfl_xor(s, 2);
        s += __shfl_xor(s, 4);
        if ((tid & 7) == 0) y2lds[brow + 32 * i] = s;
    }
    __syncthreads();

    const float c_cross = sc[2], c_y2 = sc[3];
    #pragma unroll
    for (int mi = 0; mi < 2; mi++)
        #pragma unroll
        for (int ni = 0; ni < 2; ni++) {
            int col = n0 + cn + ni * 32 + lr;
            if (col >= N_IMG) continue;
            float y2v = y2lds[cn + ni * 32 + lr];
            f32x16 v = acc[mi][ni];
            #pragma unroll
            for (int r = 0; r < 16; r++) {
                int row = m0 + rm + mi * 32 + (r & 3) + 8 * (r >> 2) + 4 * hi;
                logits[(size_t)row * N_IMG + col] = c_cross * v[r] - c_y2 * y2v;
            }
        }
}

// ---------------- fused row max + exp + row sum (writes padded eh) ----------------
__global__ void k_softmax(const float* __restrict__ logits, _Float16* __restrict__ eh,
                          float* __restrict__ rowsum) {
    int row = blockIdx.x, tid = threadIdx.x;
    const f32x4* lr = (const f32x4*)(logits + (size_t)row * N_IMG);
    _Float16* erow = eh + (size_t)row * EHS;
    f16x4* er = (f16x4*)erow;
    __shared__ float wred[4];

    if (tid < EHS - N_IMG) erow[N_IMG + tid] = (_Float16)0.f;   // zero K-tail pad

    float m = -3.0e38f;
    for (int i = tid; i < N_IMG / 4; i += 256) {
        f32x4 v = lr[i];
        m = fmaxf(m, fmaxf(fmaxf(v[0], v[1]), fmaxf(v[2], v[3])));
    }
    for (int o = 32; o > 0; o >>= 1) m = fmaxf(m, __shfl_down(m, o));
    if ((tid & 63) == 0) wred[tid >> 6] = m;
    __syncthreads();
    m = fmaxf(fmaxf(wred[0], wred[1]), fmaxf(wred[2], wred[3]));
    __syncthreads();

    float s = 0.f;
    for (int i = tid; i < N_IMG / 4; i += 256) {
        f32x4 v = lr[i];
        float e0 = __expf(v[0] - m), e1 = __expf(v[1] - m);
        float e2 = __expf(v[2] - m), e3 = __expf(v[3] - m);
        s += (e0 + e1) + (e2 + e3);
        f16x4 h;
        h[0] = (_Float16)e0; h[1] = (_Float16)e1;
        h[2] = (_Float16)e2; h[3] = (_Float16)e3;
        er[i] = h;
    }
    for (int o = 32; o > 0; o >>= 1) s += __shfl_down(s, o);
    if ((tid & 63) == 0) wred[tid >> 6] = s;
    __syncthreads();
    if (tid == 0) rowsum[row] = (wred[0] + wred[1]) + (wred[2] + wred[3]);
}

// ---------------- GEMM2: partial[ck] = eh[:,chunk] @ img[chunk,:] ----------------
// A (eh f16): glds + swizzle. B (img f32, k-strided): reg-stage, cvt->f16,
// 4x8 transpose into padded-pitch-72 LDS.
__global__ __launch_bounds__(256, 3) void k_gemm2(
        const _Float16* __restrict__ eh, const float* __restrict__ img,
        float* __restrict__ partial) {
    __shared__ _Float16 Alds[BM * BK];     // [row][k] swizzled, 16 KB
    __shared__ _Float16 Blds[BN * 72];     // [d][k] pitch 72, 18 KB

    const int tid = threadIdx.x;
    const int wid = tid >> 6, lane = tid & 63;
    const int m0 = blockIdx.x * BM;
    const int d0 = blockIdx.y * BN;
    const int ck = blockIdx.z;
    const int kbase = ck * KCHUNK;
    const int kend  = (kbase + KCHUNK < N_IMG) ? (kbase + KCHUNK) : N_IMG;
    const int iters = (kend - kbase + BK - 1) / BK;

    // A staging (glds)
    const _Float16* gA[4]; _Float16* lA[4];
    #pragma unroll
    for (int j = 0; j < 4; j++) {
        int seg = wid * 4 + j;
        int row = seg * 8 + (lane >> 3);
        int off = (((lane & 7) ^ (row & 7)) << 3);
        gA[j] = eh + (size_t)(m0 + row) * EHS + kbase + off;
        lA[j] = Alds + seg * 512;
    }
    // B staging (reg transpose from f32): thread covers 8 k-rows x 4 d
    const int bd = (tid & 31) * 4;
    const int bq = (tid >> 5) * 8;
    f32x4 breg[8];
    auto loadB = [&](int kt) {
        #pragma unroll
        for (int i = 0; i < 8; i++) {
            int k = kt + bq + i; if (k > N_IMG - 1) k = N_IMG - 1;  // dup rows: A pad=0
            breg[i] = *(const f32x4*)(img + (size_t)k * CHW + d0 + bd);
        }
    };
    auto storeB = [&]() {
        #pragma unroll
        for (int j = 0; j < 4; j++) {
            f16x8 w;
            #pragma unroll
            for (int i = 0; i < 8; i++) w[i] = (_Float16)breg[i][j];
            *(f16x8*)&Blds[(bd + j) * 72 + bq] = w;
        }
    };

    const int wm = wid >> 1, wn = wid & 1;
    const int rm = wm * 64, cn = wn * 64;
    const int lr = lane & 31, hi = lane >> 5;
    const int xm = (lr & 7) << 4;
    const char* Ab = (const char*)Alds;
    const int ar0 = (rm + lr) * 128, ar1 = (rm + 32 + lr) * 128;
    const int kof = hi * 16;

    f32x16 acc[2][2];
    #pragma unroll
    for (int mi = 0; mi < 2; mi++)
        #pragma unroll
        for (int ni = 0; ni < 2; ni++)
            #pragma unroll
            for (int r = 0; r < 16; r++) acc[mi][ni][r] = 0.f;

    loadB(kbase);
    for (int it = 0; it < iters; ++it) {
        if (it) __syncthreads();
        #pragma unroll
        for (int j = 0; j < 4; j++) glds16(gA[j] + it * BK, lA[j]);
        storeB();
        __syncthreads();
        if (it + 1 < iters) loadB(kbase + (it + 1) * BK);   // overlaps MFMA
        #pragma unroll
        for (int ks = 0; ks < 4; ++ks) {
            int offa = (ks * 32 + kof) ^ xm;
            int offb = ks * 16 + hi * 8;
            f16x8 a0 = *(const f16x8*)(Ab + ar0 + offa);
            f16x8 a1 = *(const f16x8*)(Ab + ar1 + offa);
            f16x8 b0 = *(const f16x8*)&Blds[(cn +      lr) * 72 + offb];
            f16x8 b1 = *(const f16x8*)&Blds[(cn + 32 + lr) * 72 + offb];
            acc[0][0] = __builtin_amdgcn_mfma_f32_32x32x16_f16(a0, b0, acc[0][0], 0, 0, 0);
            acc[0][1] = __builtin_amdgcn_mfma_f32_32x32x16_f16(a0, b1, acc[0][1], 0, 0, 0);
            acc[1][0] = __builtin_amdgcn_mfma_f32_32x32x16_f16(a1, b0, acc[1][0], 0, 0, 0);
            acc[1][1] = __builtin_amdgcn_mfma_f32_32x32x16_f16(a1, b1, acc[1][1], 0, 0, 0);
        }
    }

    float* pp = partial + (size_t)ck * BROWS * CHW;
    #pragma unroll
    for (int mi = 0; mi < 2; mi++)
        #pragma unroll
        for (int ni = 0; ni < 2; ni++) {
            int dcol = d0 + cn + ni * 32 + lr;
            f32x16 v = acc[mi][ni];
            #pragma unroll
            for (int r = 0; r < 16; r++) {
                int row = m0 + rm + mi * 32 + (r & 3) + 8 * (r >> 2) + 4 * hi;
                pp[(size_t)row * CHW + dcol] = v[r];
            }
        }
}

// ---------------- reduce partials + final score ----------------
__global__ void k_final(const float* __restrict__ partial, const float* __restrict__ x,
                        const float* __restrict__ rowsum, const float* __restrict__ sc,
                        float* __restrict__ out) {
    int idx = blockIdx.x * 256 + threadIdx.x;
    int row = idx / (CHW / 4);
    float at = sc[0], invbt2 = sc[4];
    float scale = at * invbt2 / rowsum[row];
    const f32x4* p4 = (const f32x4*)partial;
    f32x4 s = p4[idx];
    #pragma unroll
    for (int c = 1; c < NSPLIT; c++) s = s + p4[(size_t)c * (BROWS * CHW / 4) + idx];
    f32x4 xv = ((const f32x4*)x)[idx];
    f32x4 o;
    #pragma unroll
    for (int j = 0; j < 4; j++) o[j] = s[j] * scale - xv[j] * invbt2;
    ((f32x4*)out)[idx] = o;
}

extern "C" void kernel_launch(void* const* d_in, const int* in_sizes, int n_in,
                              void* d_out, int out_size, void* d_ws, size_t ws_size,
                              hipStream_t stream) {
    const float* t   = (const float*)d_in[0];
    const float* x   = (const float*)d_in[1];
    const float* img = (const float*)d_in[2];
    float* out = (float*)d_out;
    char* ws = (char*)d_ws;

    // ws layout (bytes)
    float*    sc     = (float*)(ws + 0);                  // 64 B
    float*    rowsum = (float*)(ws + 256);                // 1 KB
    _Float16* xh     = (_Float16*)(ws + 4096);            // 1.5 MB
    _Float16* eh     = (_Float16*)(ws + 2101248);         // 25.7 MB (stride EHS)
    float*    logits = (float*)(ws + 27791360);           // 51.2 MB
    float*    partial = logits;                           // reused (50.4 MB)

    k_scalars<<<1, 64, 0, stream>>>(t, sc);
    k_xprep<<<(BROWS * CHW / 4) / 256, 256, 0, stream>>>(x, xh);
    k_gemm1<<<dim3(2, (N_IMG + BN - 1) / BN), 256, 0, stream>>>(xh, img, sc, logits);
    k_softmax<<<256, 256, 0, stream>>>(logits, eh, rowsum);
    k_gemm2<<<dim3(2, CHW / BN, NSPLIT), 256, 0, stream>>>(eh, img, partial);
    k_final<<<(BROWS * CHW / 4) / 256, 256, 0, stream>>>(partial, x, rowsum, sc, out);
}